// Round 4
// baseline (72.121 us; speedup 1.0000x reference)
//
#include <hip/hip_runtime.h>

// Quantum state-vector simulation replacing the reference's dense-unitary build.
// out[b] = Re( M[b>>2] @ input[b] ), M = prod_{l=0..7} (ENTANGLE @ Rot(params[c,l])).
// Qubit q <-> bit (9-q) of amplitude index (kron ordering, qubit 0 = MSB).
// Entangling chain L0@L1@...@L8 (CNOT ctrl=i, tgt=i+1) applied to a vector:
// ops hit the state in order L8..L0, i.e. bit0^=bit1 first ... bit8^=bit9 last,
// each step reading an as-yet-unmodified higher bit => state'[x^(x>>1)] = state[x].
// OUTPUT: reference returns complex64; harness maps non-bf16 output to float32 =>
// out_size = 131072 f32 = real part, row-major (128,1024). (out_size==262144
// fallback keeps the bf16-interleaved interpretation just in case.)

#define DIM 1024
#define NQ 10
#define NLAYERS 8
#define NGATES (NLAYERS * NQ)  // 80

__device__ __forceinline__ unsigned short f2bf(float f) {
    unsigned int u = __float_as_uint(f);
    unsigned int r = u + 0x7FFFu + ((u >> 16) & 1u);   // round-to-nearest-even
    return (unsigned short)(r >> 16);
}

__global__ __launch_bounds__(512) void
UnitaryR3Ansatz_18846316495450_kernel(const float* __restrict__ inp,     // [128][1024] f32
                                      const float* __restrict__ params,  // [32][8][10][3] f32
                                      void* __restrict__ outp,
                                      int out_size)
{
    __shared__ float gates[NGATES][8];   // m11,m12,m21,m22 as (re,im) pairs
    __shared__ float2 bufA[DIM];
    __shared__ float2 bufB[DIM];

    const int b = blockIdx.x;     // output vector index, 0..127
    const int c = b >> 2;         // copy index (params row), repeat factor 4
    const int t = threadIdx.x;    // 0..511

    // ---- Precompute the 80 single-qubit gates for this copy ----
    if (t < NGATES) {
        const float* p = params + c * (NLAYERS * NQ * 3) + t * 3;
        const float omega = p[0], theta = p[1], phi = p[2];
        float sh, ch;  sincosf(0.5f * theta, &sh, &ch);
        float sa, ca;  sincosf(0.5f * (phi + omega), &sa, &ca);
        float sb, cb;  sincosf(0.5f * (phi - omega), &sb, &cb);
        gates[t][0] = ca * ch;  gates[t][1] = -sa * ch;   // m11 = e^{-i(phi+omega)/2} c
        gates[t][2] = -cb * sh; gates[t][3] = -sb * sh;   // m12 = -e^{+i(phi-omega)/2} s
        gates[t][4] = cb * sh;  gates[t][5] = -sb * sh;   // m21 = e^{-i(phi-omega)/2} s
        gates[t][6] = ca * ch;  gates[t][7] = sa * ch;    // m22 = e^{+i(phi+omega)/2} c
    }

    // ---- Load input vector (real) into complex LDS state ----
    const float* x = inp + b * DIM;
    bufA[t]       = make_float2(x[t], 0.0f);
    bufA[t + 512] = make_float2(x[t + 512], 0.0f);

    float2* cur = bufA;
    float2* nxt = bufB;

    for (int l = 0; l < NLAYERS; ++l) {
        // ---- 10 single-qubit rotation gates ----
        for (int q = 0; q < NQ; ++q) {
            __syncthreads();
            const int k = 9 - q;            // bit position of qubit q
            const int s = 1 << k;
            const int i0 = ((t >> k) << (k + 1)) | (t & (s - 1));
            const int i1 = i0 | s;
            const float* g = gates[l * NQ + q];
            const float2 a0 = cur[i0];
            const float2 a1 = cur[i1];
            float2 n0, n1;
            n0.x = g[0] * a0.x - g[1] * a0.y + g[2] * a1.x - g[3] * a1.y;
            n0.y = g[0] * a0.y + g[1] * a0.x + g[2] * a1.y + g[3] * a1.x;
            n1.x = g[4] * a0.x - g[5] * a0.y + g[6] * a1.x - g[7] * a1.y;
            n1.y = g[4] * a0.y + g[5] * a0.x + g[6] * a1.y + g[7] * a1.x;
            cur[i0] = n0;
            cur[i1] = n1;
        }
        // ---- Entangling chain == Gray-code permutation ----
        __syncthreads();
        {
            const int x0 = t, x1 = t + 512;
            nxt[x0 ^ (x0 >> 1)] = cur[x0];
            nxt[x1 ^ (x1 >> 1)] = cur[x1];
        }
        float2* tmp = cur; cur = nxt; nxt = tmp;
    }

    __syncthreads();

    if (out_size >= 2 * DIM * 128) {
        // 262144 elems => bf16 (re,im) interleaved
        ushort2* o2 = (ushort2*)outp + (size_t)b * DIM;
        for (int j = t; j < DIM; j += 512) {
            ushort2 v; v.x = f2bf(cur[j].x); v.y = f2bf(cur[j].y);
            o2[j] = v;
        }
    } else {
        // 131072 elems => float32 REAL PART, row-major (128,1024)
        float* of = (float*)outp + (size_t)b * DIM;
        for (int j = t; j < DIM; j += 512) {
            of[j] = cur[j].x;
        }
    }
}

extern "C" void kernel_launch(void* const* d_in, const int* in_sizes, int n_in,
                              void* d_out, int out_size, void* d_ws, size_t ws_size,
                              hipStream_t stream) {
    const float* inp    = (const float*)d_in[0];   // 131072 f32
    const float* params = (const float*)d_in[1];   // 7680 f32
    (void)in_sizes; (void)n_in; (void)d_ws; (void)ws_size;
    UnitaryR3Ansatz_18846316495450_kernel<<<128, 512, 0, stream>>>(inp, params, d_out, out_size);
}